// Round 1
// baseline (2016.716 us; speedup 1.0000x reference)
//
#include <hip/hip_runtime.h>

typedef unsigned int uint;
typedef _Float16 f16;
typedef _Float16 f16x2 __attribute__((ext_vector_type(2)));
typedef _Float16 f16x4 __attribute__((ext_vector_type(4)));
typedef _Float16 f16x8 __attribute__((ext_vector_type(8)));
typedef float f32x4 __attribute__((ext_vector_type(4)));

#define B_ 64
#define T_ 1024
#define I_ 128
#define H_ 256

__device__ __forceinline__ float fdot2u(uint w, uint h, float acc) {
  return __builtin_amdgcn_fdot2(__builtin_bit_cast(f16x2, w),
                                __builtin_bit_cast(f16x2, h), acc, false);
}

template<int CTRL>
__device__ __forceinline__ float dpp_add(float a) {
  int m = __builtin_amdgcn_update_dpp(0, __builtin_bit_cast(int, a), CTRL, 0xf, 0xf, true);
  return a + __builtin_bit_cast(float, m);
}
template<int CTRL>
__device__ __forceinline__ float dpp_mov(float a) {
  int m = __builtin_amdgcn_update_dpp(0, __builtin_bit_cast(int, a), CTRL, 0xf, 0xf, true);
  return __builtin_bit_cast(float, m);
}

// ---------------- prep: transpose x-part weights to [512 cols][K] fp16 ----------------
template<int KIN>
__global__ void prep_wxt(const float* __restrict__ Wf, const float* __restrict__ Wc,
                         f16* __restrict__ WxT) {
  int o = blockIdx.x * 256 + threadIdx.x;
  if (o >= 512 * KIN) return;
  int n = o / KIN, k = o % KIN;
  float v = (n < 256) ? Wf[k * H_ + n] : Wc[k * H_ + (n - 256)];
  WxT[o] = (f16)v;
}

// ---------------- prep: pack recurrent weights into per-thread register layout --------
// rec thread tid (wave w, lane l, g=l>>3, kq=l&7) register d (j=d>>4, kk=d&15) holds
// packed pair U[DIN + kq*32 + 2kk .. +1][ (w&3)*64 + 8g + j ], gate = w>>2 (0=f,1=c).
// flat uint index o = i*2048 + tid*4 + cmp, d = 4i+cmp  (rec loads uint4 Wp4[i*512+tid])
__global__ void prep_upack(const float* __restrict__ Wf, const float* __restrict__ Wc,
                           uint* __restrict__ Up, int DIN) {
  int o = blockIdx.x * 256 + threadIdx.x;  // 65536 total
  int i = o >> 11, tid = (o >> 2) & 511, cmp = o & 3;
  int d = 4 * i + cmp;
  int j = d >> 4, kk = d & 15;
  int w = tid >> 6, l = tid & 63, g = l >> 3, kq = l & 7;
  const float* W = (w >> 2) ? Wc : Wf;
  int col = (w & 3) * 64 + 8 * g + j;
  int k = kq * 32 + 2 * kk;
  f16x2 p = { (f16)W[(DIN + k) * H_ + col], (f16)W[(DIN + k + 1) * H_ + col] };
  Up[o] = __builtin_bit_cast(uint, p);
}

// ---------------- x-part GEMM: Xg[m][512] = A[m][K] @ WxT^T + bias (fp16 out) ---------
template<int KFULL, bool AF32>
__global__ __launch_bounds__(256) void gemm_xpart(const void* __restrict__ Av,
    const f16* __restrict__ Bt, const float* __restrict__ bf, const float* __restrict__ bc,
    f16* __restrict__ Xg) {
  __shared__ __align__(16) f16 As[128][72];   // +8 pad: kills 16-way bank conflicts
  __shared__ __align__(16) f16 Bs[128][72];
  const int m0 = blockIdx.x * 128, n0 = blockIdx.y * 128;
  const int tid = threadIdx.x, lane = tid & 63, wid = tid >> 6;
  const int wr = wid >> 1, wc = wid & 1;
  f32x4 zero4 = {0.f, 0.f, 0.f, 0.f};
  f32x4 acc[4][4];
  #pragma unroll
  for (int i = 0; i < 4; ++i)
    #pragma unroll
    for (int j = 0; j < 4; ++j) acc[i][j] = zero4;
  const int r2 = tid >> 1, hh = tid & 1;
  for (int kb = 0; kb < KFULL / 64; ++kb) {
    const int k0 = kb * 64;
    if (kb) __syncthreads();
    if (AF32) {
      const float* A = (const float*)Av;
      const float* src = A + (size_t)(m0 + r2) * KFULL + k0 + hh * 32;
      #pragma unroll
      for (int i = 0; i < 8; ++i) {
        float4 v = *(const float4*)(src + i * 4);
        f16x4 p = { (f16)v.x, (f16)v.y, (f16)v.z, (f16)v.w };
        *(f16x4*)&As[r2][hh * 32 + i * 4] = p;
      }
    } else {
      const f16* A = (const f16*)Av;
      const f16* src = A + (size_t)(m0 + r2) * KFULL + k0 + hh * 32;
      #pragma unroll
      for (int i = 0; i < 4; ++i)
        *(uint4*)&As[r2][hh * 32 + i * 8] = *(const uint4*)(src + i * 8);
    }
    {
      const f16* src = Bt + (size_t)(n0 + r2) * KFULL + k0 + hh * 32;
      #pragma unroll
      for (int i = 0; i < 4; ++i)
        *(uint4*)&Bs[r2][hh * 32 + i * 8] = *(const uint4*)(src + i * 8);
    }
    __syncthreads();
    #pragma unroll
    for (int kt = 0; kt < 2; ++kt) {
      f16x8 af[4], bfr[4];
      #pragma unroll
      for (int i = 0; i < 4; ++i)
        af[i] = *(const f16x8*)&As[wr * 64 + i * 16 + (lane & 15)][kt * 32 + (lane >> 4) * 8];
      #pragma unroll
      for (int j = 0; j < 4; ++j)
        bfr[j] = *(const f16x8*)&Bs[wc * 64 + j * 16 + (lane & 15)][kt * 32 + (lane >> 4) * 8];
      #pragma unroll
      for (int i = 0; i < 4; ++i)
        #pragma unroll
        for (int j = 0; j < 4; ++j)
          acc[i][j] = __builtin_amdgcn_mfma_f32_16x16x32_f16(af[i], bfr[j], acc[i][j], 0, 0, 0);
    }
  }
  const float* bias = (n0 < 256) ? bf : bc;
  #pragma unroll
  for (int j = 0; j < 4; ++j) {
    const int gn = n0 + wc * 64 + j * 16 + (lane & 15);
    const float bv = bias[gn & 255];
    #pragma unroll
    for (int i = 0; i < 4; ++i) {
      #pragma unroll
      for (int reg = 0; reg < 4; ++reg) {
        const int gm = m0 + wr * 64 + i * 16 + (lane >> 4) * 4 + reg;
        Xg[(size_t)gm * 512 + gn] = (f16)(acc[i][j][reg] + bv);
      }
    }
  }
}

// ---------------- persistent recurrence: 1 batch row per workgroup -------------------
// 8 waves: waves 0-3 own f-columns [64w .. 64w+64), waves 4-7 own c-columns.
// thread: C=8 cols (8g+j), K'=32 slice (kq*32..+32); weights in 128 VGPRs.
__global__ __launch_bounds__(512) void rec(const uint* __restrict__ Wp,
    const f16* __restrict__ Xg, float* __restrict__ yf, f16* __restrict__ yh,
    float* __restrict__ hid) {
  __shared__ __align__(16) uint h2s[160];   // 8 kq-blocks * (16 uints + 4 pad) -> bank-free
  __shared__ float hm[H_];
  __shared__ float carr[H_];
  const int tid = threadIdx.x, lane = tid & 63, wid = tid >> 6;
  const int wq = wid & 3, gate = wid >> 2;
  const int kq = lane & 7, r = lane & 7;
  const int b = blockIdx.x;
  const int col = wq * 64 + lane;

  uint w_u[128];
  const uint4* Wp4 = (const uint4*)Wp;
  #pragma unroll
  for (int i = 0; i < 32; ++i) {
    uint4 u = Wp4[i * 512 + tid];
    w_u[4*i+0] = u.x; w_u[4*i+1] = u.y; w_u[4*i+2] = u.z; w_u[4*i+3] = u.w;
  }

  if (tid < 160) h2s[tid] = 0u;
  if (tid < H_) hm[tid] = 0.f;
  __syncthreads();

  const size_t xoff = ((size_t)b * T_) * 512 + gate * 256 + wq * 64 + lane;
  float xcur = (float)Xg[xoff];

  #pragma unroll 1
  for (int t = 0; t < T_; ++t) {
    const int tn = (t + 1 < T_) ? t + 1 : t;
    const f16 xnf = Xg[xoff + (size_t)tn * 512];   // prefetch next step's x-part

    float acc[8];
    #pragma unroll
    for (int j = 0; j < 8; ++j) acc[j] = 0.f;
    const uint* hb = &h2s[kq * 20];
    #pragma unroll
    for (int q = 0; q < 4; ++q) {
      uint4 hv = *(const uint4*)(hb + q * 4);
      #pragma unroll
      for (int k2 = 0; k2 < 4; ++k2) {
        const uint hp = (&hv.x)[k2];
        const int kk = q * 4 + k2;
        #pragma unroll
        for (int j = 0; j < 8; ++j) acc[j] = fdot2u(w_u[j * 16 + kk], hp, acc[j]);
      }
    }
    // reduce 8 partials (lanes kq=0..7 within each 8-lane group) on the VALU pipe
    #pragma unroll
    for (int j = 0; j < 8; ++j) {
      float a = acc[j];
      a = dpp_add<0x141>(a);   // row_half_mirror: i <-> 7-i
      a = dpp_add<0x1B>(a);    // quad_perm [3,2,1,0]
      a = dpp_add<0xB1>(a);    // quad_perm [1,0,3,2]
      acc[j] = a;
    }
    // lane keeps column 8g + r  (=> col == 64wq + lane)
    float s01 = (r & 1) ? acc[1] : acc[0];
    float s23 = (r & 1) ? acc[3] : acc[2];
    float s45 = (r & 1) ? acc[5] : acc[4];
    float s67 = (r & 1) ? acc[7] : acc[6];
    float s03 = (r & 2) ? s23 : s01;
    float s47 = (r & 2) ? s67 : s45;
    float pre = ((r & 4) ? s47 : s03) + xcur;

    float fv = 0.f;
    if (gate) {
      float e2 = __expf(2.f * pre);                       // tanh = 1 - 2/(e^{2x}+1)
      carr[col] = 1.f - 2.f * __builtin_amdgcn_rcpf(e2 + 1.f);
    } else {
      fv = __builtin_amdgcn_rcpf(1.f + __expf(-pre));     // sigmoid
    }
    __syncthreads();   // B1: carr visible; all h2 reads of this step are done
    if (!gate) {
      float cv = carr[col];
      float hold = hm[col];
      float hn = cv + fv * (hold - cv);                   // f*h + (1-f)*c
      hm[col] = hn;
      if (yf) yf[((size_t)b * T_ + t) * H_ + col] = hn;
      if (yh) yh[((size_t)b * T_ + t) * H_ + col] = (f16)hn;
      if (t == T_ - 1) hid[b * H_ + col] = hn;
      float other = dpp_mov<0xB1>(hn);                    // even lane grabs odd neighbor
      if (!(lane & 1)) {
        f16x2 p = { (f16)hn, (f16)other };
        int jj = col >> 1;
        h2s[(jj >> 4) * 20 + (jj & 15)] = __builtin_bit_cast(uint, p);
      }
    }
    __syncthreads();   // B2: h2s/hm updates visible for next step
    xcur = (float)xnf;
  }
}

extern "C" void kernel_launch(void* const* d_in, const int* in_sizes, int n_in,
                              void* d_out, int out_size, void* d_ws, size_t ws_size,
                              hipStream_t stream) {
  (void)in_sizes; (void)n_in; (void)out_size; (void)ws_size;
  const float* x   = (const float*)d_in[0];
  const float* Wf1 = (const float*)d_in[1];
  const float* bf1 = (const float*)d_in[2];
  const float* Wc1 = (const float*)d_in[3];
  const float* bc1 = (const float*)d_in[4];
  const float* Wf2 = (const float*)d_in[5];
  const float* bf2 = (const float*)d_in[6];
  const float* Wc2 = (const float*)d_in[7];
  const float* bc2 = (const float*)d_in[8];
  float* out = (float*)d_out;

  char* ws = (char*)d_ws;
  f16*  Xg   = (f16*)(ws);                          // 64*1024*512*2  = 67108864 B
  f16*  y1h  = (f16*)(ws + 67108864);               // 64*1024*256*2  = 33554432 B
  f16*  Wx1T = (f16*)(ws + 100663296);              // 512*128*2      = 131072 B
  f16*  Wx2T = (f16*)(ws + 100794368);              // 512*256*2      = 262144 B
  uint* Up1  = (uint*)(ws + 101056512);             // 65536*4        = 262144 B
  uint* Up2  = (uint*)(ws + 101318656);             // 65536*4        = 262144 B

  float* y2   = out;                                // [64,1024,256]
  float* hid1 = out + (size_t)B_ * T_ * H_;         // [64,256]
  float* hid2 = hid1 + (size_t)B_ * H_;             // [64,256]

  prep_wxt<128><<<256, 256, 0, stream>>>(Wf1, Wc1, Wx1T);
  prep_wxt<256><<<512, 256, 0, stream>>>(Wf2, Wc2, Wx2T);
  prep_upack<<<256, 256, 0, stream>>>(Wf1, Wc1, Up1, 128);
  prep_upack<<<256, 256, 0, stream>>>(Wf2, Wc2, Up2, 256);

  gemm_xpart<128, true ><<<dim3(512, 4), 256, 0, stream>>>(x,   Wx1T, bf1, bc1, Xg);
  rec<<<64, 512, 0, stream>>>(Up1, Xg, nullptr, y1h, hid1);
  gemm_xpart<256, false><<<dim3(512, 4), 256, 0, stream>>>(y1h, Wx2T, bf2, bc2, Xg);
  rec<<<64, 512, 0, stream>>>(Up2, Xg, y2, nullptr, hid2);
}

// Round 2
// 2013.512 us; speedup vs baseline: 1.0016x; 1.0016x over previous
//
#include <hip/hip_runtime.h>

typedef unsigned int uint;
typedef _Float16 f16;
typedef _Float16 f16x2 __attribute__((ext_vector_type(2)));
typedef _Float16 f16x4 __attribute__((ext_vector_type(4)));
typedef _Float16 f16x8 __attribute__((ext_vector_type(8)));
typedef float f32x4 __attribute__((ext_vector_type(4)));

#define B_ 64
#define T_ 1024
#define I_ 128
#define H_ 256

__device__ __forceinline__ float fdot2u(uint w, uint h, float acc) {
  return __builtin_amdgcn_fdot2(__builtin_bit_cast(f16x2, w),
                                __builtin_bit_cast(f16x2, h), acc, false);
}

template<int CTRL>
__device__ __forceinline__ float dpp_add(float a) {
  int m = __builtin_amdgcn_update_dpp(0, __builtin_bit_cast(int, a), CTRL, 0xf, 0xf, true);
  return a + __builtin_bit_cast(float, m);
}
template<int CTRL>
__device__ __forceinline__ float dpp_mov(float a) {
  int m = __builtin_amdgcn_update_dpp(0, __builtin_bit_cast(int, a), CTRL, 0xf, 0xf, true);
  return __builtin_bit_cast(float, m);
}

// ---------------- prep: transpose x-part weights to [512 cols][K] fp16 ----------------
template<int KIN>
__global__ void prep_wxt(const float* __restrict__ Wf, const float* __restrict__ Wc,
                         f16* __restrict__ WxT) {
  int o = blockIdx.x * 256 + threadIdx.x;
  if (o >= 512 * KIN) return;
  int n = o / KIN, k = o % KIN;
  float v = (n < 256) ? Wf[k * H_ + n] : Wc[k * H_ + (n - 256)];
  WxT[o] = (f16)v;
}

// ---------------- prep: pack recurrent weights into per-thread register layout --------
// rec thread tid (wave w, lane l, g=l>>3, kq=l&7) register d (j=d>>4, kk=d&15) holds
// packed pair U[DIN + kq*32 + 2kk .. +1][ (w&3)*64 + 8g + j ], gate = w>>2 (0=f,1=c).
// flat uint index o = i*2048 + tid*4 + cmp, d = 4i+cmp  (rec loads uint4 Wp4[i*512+tid])
__global__ void prep_upack(const float* __restrict__ Wf, const float* __restrict__ Wc,
                           uint* __restrict__ Up, int DIN) {
  int o = blockIdx.x * 256 + threadIdx.x;  // 65536 total
  int i = o >> 11, tid = (o >> 2) & 511, cmp = o & 3;
  int d = 4 * i + cmp;
  int j = d >> 4, kk = d & 15;
  int w = tid >> 6, l = tid & 63, g = l >> 3, kq = l & 7;
  const float* W = (w >> 2) ? Wc : Wf;
  int col = (w & 3) * 64 + 8 * g + j;
  int k = kq * 32 + 2 * kk;
  f16x2 p = { (f16)W[(DIN + k) * H_ + col], (f16)W[(DIN + k + 1) * H_ + col] };
  Up[o] = __builtin_bit_cast(uint, p);
}

// ---------------- x-part GEMM: Xg[m][512] = A[m][K] @ WxT^T + bias (fp16 out) ---------
template<int KFULL, bool AF32>
__global__ __launch_bounds__(256) void gemm_xpart(const void* __restrict__ Av,
    const f16* __restrict__ Bt, const float* __restrict__ bf, const float* __restrict__ bc,
    f16* __restrict__ Xg) {
  __shared__ __align__(16) f16 As[128][72];   // +8 pad: kills 16-way bank conflicts
  __shared__ __align__(16) f16 Bs[128][72];
  const int m0 = blockIdx.x * 128, n0 = blockIdx.y * 128;
  const int tid = threadIdx.x, lane = tid & 63, wid = tid >> 6;
  const int wr = wid >> 1, wc = wid & 1;
  f32x4 zero4 = {0.f, 0.f, 0.f, 0.f};
  f32x4 acc[4][4];
  #pragma unroll
  for (int i = 0; i < 4; ++i)
    #pragma unroll
    for (int j = 0; j < 4; ++j) acc[i][j] = zero4;
  const int r2 = tid >> 1, hh = tid & 1;
  for (int kb = 0; kb < KFULL / 64; ++kb) {
    const int k0 = kb * 64;
    if (kb) __syncthreads();
    if (AF32) {
      const float* A = (const float*)Av;
      const float* src = A + (size_t)(m0 + r2) * KFULL + k0 + hh * 32;
      #pragma unroll
      for (int i = 0; i < 8; ++i) {
        float4 v = *(const float4*)(src + i * 4);
        f16x4 p = { (f16)v.x, (f16)v.y, (f16)v.z, (f16)v.w };
        *(f16x4*)&As[r2][hh * 32 + i * 4] = p;
      }
    } else {
      const f16* A = (const f16*)Av;
      const f16* src = A + (size_t)(m0 + r2) * KFULL + k0 + hh * 32;
      #pragma unroll
      for (int i = 0; i < 4; ++i)
        *(uint4*)&As[r2][hh * 32 + i * 8] = *(const uint4*)(src + i * 8);
    }
    {
      const f16* src = Bt + (size_t)(n0 + r2) * KFULL + k0 + hh * 32;
      #pragma unroll
      for (int i = 0; i < 4; ++i)
        *(uint4*)&Bs[r2][hh * 32 + i * 8] = *(const uint4*)(src + i * 8);
    }
    __syncthreads();
    #pragma unroll
    for (int kt = 0; kt < 2; ++kt) {
      f16x8 af[4], bfr[4];
      #pragma unroll
      for (int i = 0; i < 4; ++i)
        af[i] = *(const f16x8*)&As[wr * 64 + i * 16 + (lane & 15)][kt * 32 + (lane >> 4) * 8];
      #pragma unroll
      for (int j = 0; j < 4; ++j)
        bfr[j] = *(const f16x8*)&Bs[wc * 64 + j * 16 + (lane & 15)][kt * 32 + (lane >> 4) * 8];
      #pragma unroll
      for (int i = 0; i < 4; ++i)
        #pragma unroll
        for (int j = 0; j < 4; ++j)
          acc[i][j] = __builtin_amdgcn_mfma_f32_16x16x32_f16(af[i], bfr[j], acc[i][j], 0, 0, 0);
    }
  }
  const float* bias = (n0 < 256) ? bf : bc;
  #pragma unroll
  for (int j = 0; j < 4; ++j) {
    const int gn = n0 + wc * 64 + j * 16 + (lane & 15);
    const float bv = bias[gn & 255];
    #pragma unroll
    for (int i = 0; i < 4; ++i) {
      #pragma unroll
      for (int reg = 0; reg < 4; ++reg) {
        const int gm = m0 + wr * 64 + i * 16 + (lane >> 4) * 4 + reg;
        Xg[(size_t)gm * 512 + gn] = (f16)(acc[i][j][reg] + bv);
      }
    }
  }
}

// ---------------- persistent recurrence: 1 batch row per workgroup -------------------
// 8 waves: waves 0-3 own f-columns [64w .. 64w+64), waves 4-7 own c-columns.
// thread: C=8 cols (8g+j), K'=32 slice (kq*32..+32); weights in 128 VGPRs.
// __launch_bounds__(512, 2): 2 waves/EU -> 256-VGPR budget so the 32x uint4
// weight array stays register-resident (R1: default heuristic spilled it, VGPR=84).
__global__ __launch_bounds__(512, 2) void rec(const uint* __restrict__ Wp,
    const f16* __restrict__ Xg, float* __restrict__ yf, f16* __restrict__ yh,
    float* __restrict__ hid) {
  __shared__ __align__(16) uint h2s[160];   // 8 kq-blocks * (16 uints + 4 pad) -> bank-free
  __shared__ float hm[H_];
  __shared__ float carr[H_];
  const int tid = threadIdx.x, lane = tid & 63, wid = tid >> 6;
  const int wq = wid & 3, gate = wid >> 2;
  const int kq = lane & 7, r = lane & 7;
  const int b = blockIdx.x;
  const int col = wq * 64 + lane;

  // weights for this thread: wv[j*4+q] component k2 = packed pair for
  // (col j, k-pair kk=q*4+k2); all indices compile-time after unroll -> SROA to VGPRs
  uint4 wv[32];
  const uint4* Wp4 = (const uint4*)Wp;
  #pragma unroll
  for (int i = 0; i < 32; ++i) wv[i] = Wp4[i * 512 + tid];

  if (tid < 160) h2s[tid] = 0u;
  if (tid < H_) hm[tid] = 0.f;
  __syncthreads();

  const size_t xoff = ((size_t)b * T_) * 512 + gate * 256 + wq * 64 + lane;
  float xcur = (float)Xg[xoff];

  #pragma unroll 1
  for (int t = 0; t < T_; ++t) {
    const int tn = (t + 1 < T_) ? t + 1 : t;
    const f16 xnf = Xg[xoff + (size_t)tn * 512];   // prefetch next step's x-part

    float acc[8];
    #pragma unroll
    for (int j = 0; j < 8; ++j) acc[j] = 0.f;
    const uint* hb = &h2s[kq * 20];
    #pragma unroll
    for (int q = 0; q < 4; ++q) {
      uint4 hv = *(const uint4*)(hb + q * 4);
      #pragma unroll
      for (int k2 = 0; k2 < 4; ++k2) {
        const uint hp = (k2 == 0) ? hv.x : (k2 == 1) ? hv.y : (k2 == 2) ? hv.z : hv.w;
        #pragma unroll
        for (int j = 0; j < 8; ++j) {
          const uint4 w4 = wv[j * 4 + q];
          const uint wu = (k2 == 0) ? w4.x : (k2 == 1) ? w4.y : (k2 == 2) ? w4.z : w4.w;
          acc[j] = fdot2u(wu, hp, acc[j]);
        }
      }
    }
    // reduce 8 partials (lanes kq=0..7 within each 8-lane group) on the VALU pipe
    #pragma unroll
    for (int j = 0; j < 8; ++j) {
      float a = acc[j];
      a = dpp_add<0x141>(a);   // row_half_mirror: i <-> 7-i
      a = dpp_add<0x1B>(a);    // quad_perm [3,2,1,0]
      a = dpp_add<0xB1>(a);    // quad_perm [1,0,3,2]
      acc[j] = a;
    }
    // lane keeps column 8g + r  (=> col == 64wq + lane)
    float s01 = (r & 1) ? acc[1] : acc[0];
    float s23 = (r & 1) ? acc[3] : acc[2];
    float s45 = (r & 1) ? acc[5] : acc[4];
    float s67 = (r & 1) ? acc[7] : acc[6];
    float s03 = (r & 2) ? s23 : s01;
    float s47 = (r & 2) ? s67 : s45;
    float pre = ((r & 4) ? s47 : s03) + xcur;

    float fv = 0.f;
    if (gate) {
      float e2 = __expf(2.f * pre);                       // tanh = 1 - 2/(e^{2x}+1)
      carr[col] = 1.f - 2.f * __builtin_amdgcn_rcpf(e2 + 1.f);
    } else {
      fv = __builtin_amdgcn_rcpf(1.f + __expf(-pre));     // sigmoid
    }
    __syncthreads();   // B1: carr visible; all h2 reads of this step are done
    if (!gate) {
      float cv = carr[col];
      float hold = hm[col];
      float hn = cv + fv * (hold - cv);                   // f*h + (1-f)*c
      hm[col] = hn;
      if (yf) yf[((size_t)b * T_ + t) * H_ + col] = hn;
      if (yh) yh[((size_t)b * T_ + t) * H_ + col] = (f16)hn;
      if (t == T_ - 1) hid[b * H_ + col] = hn;
      float other = dpp_mov<0xB1>(hn);                    // even lane grabs odd neighbor
      if (!(lane & 1)) {
        f16x2 p = { (f16)hn, (f16)other };
        int jj = col >> 1;
        h2s[(jj >> 4) * 20 + (jj & 15)] = __builtin_bit_cast(uint, p);
      }
    }
    __syncthreads();   // B2: h2s/hm updates visible for next step
    xcur = (float)xnf;
  }
}

extern "C" void kernel_launch(void* const* d_in, const int* in_sizes, int n_in,
                              void* d_out, int out_size, void* d_ws, size_t ws_size,
                              hipStream_t stream) {
  (void)in_sizes; (void)n_in; (void)out_size; (void)ws_size;
  const float* x   = (const float*)d_in[0];
  const float* Wf1 = (const float*)d_in[1];
  const float* bf1 = (const float*)d_in[2];
  const float* Wc1 = (const float*)d_in[3];
  const float* bc1 = (const float*)d_in[4];
  const float* Wf2 = (const float*)d_in[5];
  const float* bf2 = (const float*)d_in[6];
  const float* Wc2 = (const float*)d_in[7];
  const float* bc2 = (const float*)d_in[8];
  float* out = (float*)d_out;

  char* ws = (char*)d_ws;
  f16*  Xg   = (f16*)(ws);                          // 64*1024*512*2  = 67108864 B
  f16*  y1h  = (f16*)(ws + 67108864);               // 64*1024*256*2  = 33554432 B
  f16*  Wx1T = (f16*)(ws + 100663296);              // 512*128*2      = 131072 B
  f16*  Wx2T = (f16*)(ws + 100794368);              // 512*256*2      = 262144 B
  uint* Up1  = (uint*)(ws + 101056512);             // 65536*4        = 262144 B
  uint* Up2  = (uint*)(ws + 101318656);             // 65536*4        = 262144 B

  float* y2   = out;                                // [64,1024,256]
  float* hid1 = out + (size_t)B_ * T_ * H_;         // [64,256]
  float* hid2 = hid1 + (size_t)B_ * H_;             // [64,256]

  prep_wxt<128><<<256, 256, 0, stream>>>(Wf1, Wc1, Wx1T);
  prep_wxt<256><<<512, 256, 0, stream>>>(Wf2, Wc2, Wx2T);
  prep_upack<<<256, 256, 0, stream>>>(Wf1, Wc1, Up1, 128);
  prep_upack<<<256, 256, 0, stream>>>(Wf2, Wc2, Up2, 256);

  gemm_xpart<128, true ><<<dim3(512, 4), 256, 0, stream>>>(x,   Wx1T, bf1, bc1, Xg);
  rec<<<64, 512, 0, stream>>>(Up1, Xg, nullptr, y1h, hid1);
  gemm_xpart<256, false><<<dim3(512, 4), 256, 0, stream>>>(y1h, Wx2T, bf2, bc2, Xg);
  rec<<<64, 512, 0, stream>>>(Up2, Xg, y2, nullptr, hid2);
}